// Round 4
// baseline (321.918 us; speedup 1.0000x reference)
//
#include <hip/hip_runtime.h>

#define WW 320          // input width/height
#define OWID 314        // output cols
#define OHEI 314        // output rows
#define BB 64           // batch
#define RPB 12          // output rows per band (2 unrolled chunks of 6)
#define NBAND 27        // 26 full bands + one 2-row band (314 = 12*26 + 2)
#define NSTRIP 79       // ceil(314/4) output-col strips of 4
#define NTH 256
#define TOTAL (BB * NBAND * NSTRIP)          // 136512
#define NBLK ((TOTAL + NTH - 1) / NTH)       // 534

// Horizontal 7-tap sums of the 5 channel-combined moments for one input row.
// h[q*4+j], q in {sx,sy,sxx,syy,sxy}, j = output col within strip.
__device__ __forceinline__ void compute_h(
    const float* __restrict__ X0, const float* __restrict__ X1,
    const float* __restrict__ Y0, const float* __restrict__ Y1,
    int off, int o2, float h[20])
{
    float m[5][10];
    {   // plane pair 0 (channel 0 of X and Y)
        float4 a0 = *(const float4*)(X0 + off);
        float4 a1 = *(const float4*)(X0 + off + 4);
        float4 a2 = *(const float4*)(X0 + off + o2);
        float4 b0 = *(const float4*)(Y0 + off);
        float4 b1 = *(const float4*)(Y0 + off + 4);
        float4 b2 = *(const float4*)(Y0 + off + o2);
        float xa[10] = {a0.x,a0.y,a0.z,a0.w,a1.x,a1.y,a1.z,a1.w,a2.x,a2.y};
        float ya[10] = {b0.x,b0.y,b0.z,b0.w,b1.x,b1.y,b1.z,b1.w,b2.x,b2.y};
        #pragma unroll
        for (int j = 0; j < 10; ++j) {
            m[0][j] = xa[j];
            m[1][j] = ya[j];
            m[2][j] = xa[j] * xa[j];
            m[3][j] = ya[j] * ya[j];
            m[4][j] = xa[j] * ya[j];
        }
    }
    {   // plane pair 1 (channel 1), accumulate
        float4 a0 = *(const float4*)(X1 + off);
        float4 a1 = *(const float4*)(X1 + off + 4);
        float4 a2 = *(const float4*)(X1 + off + o2);
        float4 b0 = *(const float4*)(Y1 + off);
        float4 b1 = *(const float4*)(Y1 + off + 4);
        float4 b2 = *(const float4*)(Y1 + off + o2);
        float xa[10] = {a0.x,a0.y,a0.z,a0.w,a1.x,a1.y,a1.z,a1.w,a2.x,a2.y};
        float ya[10] = {b0.x,b0.y,b0.z,b0.w,b1.x,b1.y,b1.z,b1.w,b2.x,b2.y};
        #pragma unroll
        for (int j = 0; j < 10; ++j) {
            m[0][j] += xa[j];
            m[1][j] += ya[j];
            m[2][j] = fmaf(xa[j], xa[j], m[2][j]);
            m[3][j] = fmaf(ya[j], ya[j], m[3][j]);
            m[4][j] = fmaf(xa[j], ya[j], m[4][j]);
        }
    }
    #pragma unroll
    for (int q = 0; q < 5; ++q) {
        float t0 = ((m[q][0] + m[q][1]) + (m[q][2] + m[q][3])) + ((m[q][4] + m[q][5]) + m[q][6]);
        float t1 = t0 - m[q][0] + m[q][7];
        float t2 = t1 - m[q][1] + m[q][8];
        float t3 = t2 - m[q][2] + m[q][9];
        h[q * 4 + 0] = t0; h[q * 4 + 1] = t1; h[q * 4 + 2] = t2; h[q * 4 + 3] = t3;
    }
}

__global__ __launch_bounds__(NTH, 2) void ssim_main(
    const float* __restrict__ X, const float* __restrict__ Y,
    const float* __restrict__ dr, double* __restrict__ acc,
    unsigned* __restrict__ counter, float* __restrict__ out)
{
    const int wi     = blockIdx.x * NTH + threadIdx.x;
    const bool active = (wi < TOTAL);

    float ssum = 0.0f;
    if (active) {
        const int s    = wi % NSTRIP;
        const int g    = wi / NSTRIP;
        const int band = g % NBAND;
        const int b    = g / NBAND;
        const int r0   = band * RPB;
        const int r1   = min(r0 + RPB, OHEI);
        const int cb   = s * 4;
        const int o2   = (cb <= 308) ? 8 : 4;   // clamp 3rd float4 for last strip

        const size_t plane = (size_t)WW * WW;
        const float* X0 = X + (size_t)b * 2 * plane;
        const float* X1 = X0 + plane;
        const float* Y0 = Y + (size_t)b * 2 * plane;
        const float* Y1 = Y0 + plane;

        // SSIM constants folded to raw-window-sum form (x49^2)
        const float d   = dr[b];
        const float C1p = 2401.0f * (0.01f * d) * (0.01f * d);
        const float C2p = 2401.0f * (0.03f * d) * (0.03f * d);
        const float cn  = 49.0f / 48.0f;

        float cm[4];
        #pragma unroll
        for (int j = 0; j < 4; ++j) cm[j] = (cb + j < OWID) ? 1.0f : 0.0f;

        float hist[6][20];   // ring of horizontal sums, rows t..t+5
        float v[20];
        #pragma unroll
        for (int i = 0; i < 20; ++i) v[i] = 0.0f;

        // warm-up: rows r0 .. r0+5 into ring
        #pragma unroll
        for (int k = 0; k < 6; ++k) {
            compute_h(X0, X1, Y0, Y1, (r0 + k) * WW + cb, o2, hist[k]);
            #pragma unroll
            for (int i = 0; i < 20; ++i) v[i] += hist[k][i];
        }

        // emit SSIM for one output row from raw window sums v
        auto emit = [&](const float* vv) {
            #pragma unroll
            for (int j = 0; j < 4; ++j) {
                const float V0 = vv[j],      V1 = vv[4 + j];
                const float V2 = vv[8 + j],  V3 = vv[12 + j], V4 = vv[16 + j];
                const float t01 = V0 * V1;
                const float t00 = V0 * V0;
                const float t11 = V1 * V1;
                const float A1  = 2.0f * t01 + C1p;
                const float A2  = fmaf(2.0f * cn, fmaf(49.0f, V4, -t01), C2p);
                const float B1  = t00 + t11 + C1p;
                const float p0  = fmaf(49.0f, V2, -t00);
                const float p1  = fmaf(49.0f, V3, -t11);
                const float B2  = fmaf(cn, p0 + p1, C2p);
                ssum = fmaf(cm[j], (A1 * A2) * __builtin_amdgcn_rcpf(B1 * B2), ssum);
            }
        };

        const int nfull = (r1 - r0) / 6;     // 2 for full bands, 0 for last band
        int t = r0;
        for (int c = 0; c < nfull; ++c) {
            #pragma unroll
            for (int u = 0; u < 6; ++u) {
                float hn[20];
                compute_h(X0, X1, Y0, Y1, (t + u + 6) * WW + cb, o2, hn);
                #pragma unroll
                for (int i = 0; i < 20; ++i) v[i] += hn[i];
                emit(v);
                #pragma unroll
                for (int i = 0; i < 20; ++i) v[i] -= hist[u][i];
                #pragma unroll
                for (int i = 0; i < 20; ++i) hist[u][i] = hn[i];
            }
            t += 6;
        }
        // ragged remainder (last band only): re-load row t for the subtract
        for (; t < r1; ++t) {
            float hn[20];
            compute_h(X0, X1, Y0, Y1, (t + 6) * WW + cb, o2, hn);
            #pragma unroll
            for (int i = 0; i < 20; ++i) v[i] += hn[i];
            emit(v);
            float ho[20];
            compute_h(X0, X1, Y0, Y1, t * WW + cb, o2, ho);
            #pragma unroll
            for (int i = 0; i < 20; ++i) v[i] -= ho[i];
        }
    }

    // ---- reduction: wave shuffle (double) -> LDS -> one atomic per block ----
    double local = (double)ssum;
    #pragma unroll
    for (int off = 32; off > 0; off >>= 1)
        local += __shfl_down(local, off, 64);
    __shared__ double wsum[NTH / 64];
    const int lane = threadIdx.x & 63, wid = threadIdx.x >> 6;
    if (lane == 0) wsum[wid] = local;
    __syncthreads();
    if (threadIdx.x == 0) {
        double tot = (wsum[0] + wsum[1]) + (wsum[2] + wsum[3]);
        atomicAdd(acc, tot);
        __threadfence();
        unsigned ticket = atomicAdd(counter, 1u);
        if (ticket == NBLK - 1) {
            double stot = atomicAdd(acc, 0.0);   // device-scope coherent read
            const double N = (double)BB * (double)OHEI * (double)OWID;
            out[0] = (float)(1.0 - stot / N);
        }
    }
}

extern "C" void kernel_launch(void* const* d_in, const int* in_sizes, int n_in,
                              void* d_out, int out_size, void* d_ws, size_t ws_size,
                              hipStream_t stream)
{
    const float* X  = (const float*)d_in[0];
    const float* Y  = (const float*)d_in[1];
    const float* dr = (const float*)d_in[2];
    // d_in[3] is the box kernel w (all 1/49) — folded into constants.
    double*   acc     = (double*)d_ws;
    unsigned* counter = (unsigned*)((char*)d_ws + 8);
    float*    out     = (float*)d_out;

    hipMemsetAsync(d_ws, 0, 16, stream);
    ssim_main<<<dim3(NBLK), dim3(NTH), 0, stream>>>(X, Y, dr, acc, counter, out);
}

// Round 5
// 245.542 us; speedup vs baseline: 1.3110x; 1.3110x over previous
//
#include <hip/hip_runtime.h>

#define WW 320          // input width/height
#define OWID 314        // output cols
#define OHEI 314        // output rows
#define BB 64           // batch
#define TILE_C 64       // output cols per block
#define TILE_R 32       // output rows per block
#define NCT 5           // ceil(314/64)
#define NBD 10          // ceil(314/32)
#define NTH 256
#define NBLK (BB * NCT * NBD)    // 3200
#define NROWS (TILE_R + 6)       // 38 hs rows per tile
#define NUNITS (NROWS * 16)      // 608 production units (row, strip)

__global__ __launch_bounds__(NTH) void ssim_main(
    const float* __restrict__ X, const float* __restrict__ Y,
    const float* __restrict__ dr, double* __restrict__ acc,
    unsigned* __restrict__ counter, float* __restrict__ out)
{
    __shared__ float hs[5][NROWS][TILE_C];   // 48640 B
    __shared__ double wsum[NTH / 64];

    const int blk  = blockIdx.x;
    const int b    = blk / (NCT * NBD);
    const int rem  = blk % (NCT * NBD);
    const int ct   = rem / NBD;
    const int band = rem % NBD;
    const int c0   = ct * TILE_C;
    const int r0   = band * TILE_R;

    const size_t plane = (size_t)WW * WW;
    const float* X0 = X + (size_t)b * 2 * plane;
    const float* X1 = X0 + plane;
    const float* Y0 = Y + (size_t)b * 2 * plane;
    const float* Y1 = Y0 + plane;

    // ---------------- Phase 1: produce horizontal 7-tap moment sums ---------
    for (int u = threadIdx.x; u < NUNITS; u += NTH) {
        const int strip = u & 15;
        const int row   = u >> 4;
        const int r_abs = min(r0 + row, WW - 1);      // clamp last band
        const int base  = c0 + strip * 4;
        const int a0 = min(base,     316);            // keep all float4 loads in-bounds
        const int a1 = min(base + 4, 316);
        const int a2 = min(base + 8, 316);
        const int ro = r_abs * WW;

        float m[5][10];
        {   // channel 0
            float4 p0 = *(const float4*)(X0 + ro + a0);
            float4 p1 = *(const float4*)(X0 + ro + a1);
            float4 p2 = *(const float4*)(X0 + ro + a2);
            float4 q0 = *(const float4*)(Y0 + ro + a0);
            float4 q1 = *(const float4*)(Y0 + ro + a1);
            float4 q2 = *(const float4*)(Y0 + ro + a2);
            float xa[10] = {p0.x,p0.y,p0.z,p0.w,p1.x,p1.y,p1.z,p1.w,p2.x,p2.y};
            float ya[10] = {q0.x,q0.y,q0.z,q0.w,q1.x,q1.y,q1.z,q1.w,q2.x,q2.y};
            #pragma unroll
            for (int j = 0; j < 10; ++j) {
                m[0][j] = xa[j];
                m[1][j] = ya[j];
                m[2][j] = xa[j] * xa[j];
                m[3][j] = ya[j] * ya[j];
                m[4][j] = xa[j] * ya[j];
            }
        }
        {   // channel 1
            float4 p0 = *(const float4*)(X1 + ro + a0);
            float4 p1 = *(const float4*)(X1 + ro + a1);
            float4 p2 = *(const float4*)(X1 + ro + a2);
            float4 q0 = *(const float4*)(Y1 + ro + a0);
            float4 q1 = *(const float4*)(Y1 + ro + a1);
            float4 q2 = *(const float4*)(Y1 + ro + a2);
            float xa[10] = {p0.x,p0.y,p0.z,p0.w,p1.x,p1.y,p1.z,p1.w,p2.x,p2.y};
            float ya[10] = {q0.x,q0.y,q0.z,q0.w,q1.x,q1.y,q1.z,q1.w,q2.x,q2.y};
            #pragma unroll
            for (int j = 0; j < 10; ++j) {
                m[0][j] += xa[j];
                m[1][j] += ya[j];
                m[2][j] = fmaf(xa[j], xa[j], m[2][j]);
                m[3][j] = fmaf(ya[j], ya[j], m[3][j]);
                m[4][j] = fmaf(xa[j], ya[j], m[4][j]);
            }
        }
        #pragma unroll
        for (int q = 0; q < 5; ++q) {
            float t0 = ((m[q][0] + m[q][1]) + (m[q][2] + m[q][3])) + ((m[q][4] + m[q][5]) + m[q][6]);
            float t1 = t0 - m[q][0] + m[q][7];
            float t2 = t1 - m[q][1] + m[q][8];
            float t3 = t2 - m[q][2] + m[q][9];
            *(float4*)&hs[q][row][strip * 4] = make_float4(t0, t1, t2, t3);
        }
    }

    __syncthreads();   // the only barrier

    // ---------------- Phase 2: vertical sliding window + SSIM ---------------
    const int col = threadIdx.x & 63;
    const int g   = threadIdx.x >> 6;
    const int ob  = g * 8;                       // band-local first output row
    const bool cvalid = (c0 + col < OWID);

    const float d   = dr[b];
    const float C1p = 2401.0f * (0.01f * d) * (0.01f * d);
    const float C2p = 2401.0f * (0.03f * d) * (0.03f * d);
    const float cn  = 49.0f / 48.0f;

    float v[5];
    #pragma unroll
    for (int q = 0; q < 5; ++q) {
        v[q] = ((hs[q][ob][col]     + hs[q][ob + 1][col]) +
                (hs[q][ob + 2][col] + hs[q][ob + 3][col])) +
                (hs[q][ob + 4][col] + hs[q][ob + 5][col]);
    }

    float ssum = 0.0f;
    #pragma unroll
    for (int k = 0; k < 8; ++k) {
        const int o = ob + k;
        #pragma unroll
        for (int q = 0; q < 5; ++q) v[q] += hs[q][o + 6][col];

        if (cvalid && (r0 + o < OHEI)) {
            const float V0 = v[0], V1 = v[1], V2 = v[2], V3 = v[3], V4 = v[4];
            const float t01 = V0 * V1;
            const float t00 = V0 * V0;
            const float t11 = V1 * V1;
            const float A1  = 2.0f * t01 + C1p;
            const float A2  = fmaf(2.0f * cn, fmaf(49.0f, V4, -t01), C2p);
            const float B1  = t00 + t11 + C1p;
            const float p0  = fmaf(49.0f, V2, -t00);
            const float p1  = fmaf(49.0f, V3, -t11);
            const float B2  = fmaf(cn, p0 + p1, C2p);
            ssum += (A1 * A2) * __builtin_amdgcn_rcpf(B1 * B2);
        }

        #pragma unroll
        for (int q = 0; q < 5; ++q) v[q] -= hs[q][o][col];
    }

    // ---- reduction: wave shuffle (double) -> LDS -> one atomic per block ----
    double local = (double)ssum;
    #pragma unroll
    for (int off = 32; off > 0; off >>= 1)
        local += __shfl_down(local, off, 64);
    const int lane = threadIdx.x & 63, wid = threadIdx.x >> 6;
    if (lane == 0) wsum[wid] = local;
    __syncthreads();
    if (threadIdx.x == 0) {
        double tot = (wsum[0] + wsum[1]) + (wsum[2] + wsum[3]);
        atomicAdd(acc, tot);
        __threadfence();
        unsigned ticket = atomicAdd(counter, 1u);
        if (ticket == NBLK - 1) {
            double stot = atomicAdd(acc, 0.0);   // device-scope coherent read
            const double N = (double)BB * (double)OHEI * (double)OWID;
            out[0] = (float)(1.0 - stot / N);
        }
    }
}

extern "C" void kernel_launch(void* const* d_in, const int* in_sizes, int n_in,
                              void* d_out, int out_size, void* d_ws, size_t ws_size,
                              hipStream_t stream)
{
    const float* X  = (const float*)d_in[0];
    const float* Y  = (const float*)d_in[1];
    const float* dr = (const float*)d_in[2];
    // d_in[3] is the box kernel w (all 1/49) — folded into constants.
    double*   acc     = (double*)d_ws;
    unsigned* counter = (unsigned*)((char*)d_ws + 8);
    float*    out     = (float*)d_out;

    hipMemsetAsync(d_ws, 0, 16, stream);
    ssim_main<<<dim3(NBLK), dim3(NTH), 0, stream>>>(X, Y, dr, acc, counter, out);
}

// Round 6
// 220.099 us; speedup vs baseline: 1.4626x; 1.1156x over previous
//
#include <hip/hip_runtime.h>

#define WW 320          // input width/height
#define OWID 314        // output cols
#define OHEI 314        // output rows
#define BB 64           // batch
#define RPB 16          // output rows per wave-unit
#define NBAND 20        // ceil(314/16)
#define CGW 58          // output cols per wave (64 lanes, 58 valid windows)
#define NCG 6           // ceil(314/58)
#define NTH 256
#define WPB 4           // waves per block
#define NWU (BB * NCG * NBAND)   // 7680 wave-units
#define NBLK (NWU / WPB)         // 1920 exactly

// 7-tap horizontal sum across lanes: h[i] = m[i]+...+m[i+6]; valid for lane<=57.
__device__ __forceinline__ float hsum7(float m, int lane) {
    float s1 = m + __shfl(m, lane + 1, 64);    // 2-tap
    float s2 = s1 + __shfl(s1, lane + 2, 64);  // 4-tap
    float s4 = s2 + __shfl(s2, lane + 4, 64);  // 8-tap
    return s4 - __shfl(m, lane + 7, 64);       // 7-tap
}

__global__ __launch_bounds__(NTH, 6) void ssim_main(
    const float* __restrict__ X, const float* __restrict__ Y,
    const float* __restrict__ dr, double* __restrict__ acc,
    unsigned* __restrict__ counter, float* __restrict__ out)
{
    const int lane = threadIdx.x & 63;
    const int wu   = blockIdx.x * WPB + (threadIdx.x >> 6);
    const int band = wu % NBAND;
    const int g    = (wu / NBAND) % NCG;
    const int b    = wu / (NBAND * NCG);
    const int r0   = band * RPB;
    const int cbase = g * CGW;
    const int c     = cbase + lane;
    const int cl    = min(c, WW - 1);             // clamped load col
    const bool oval = (lane < 58) && (c < OWID);  // this lane emits outputs

    const size_t plane = (size_t)WW * WW;
    const float* X0 = X + (size_t)b * 2 * plane;
    const float* X1 = X0 + plane;
    const float* Y0 = Y + (size_t)b * 2 * plane;
    const float* Y1 = Y0 + plane;

    // SSIM constants folded to raw-window-sum form (x49^2)
    const float d   = dr[b];
    const float C1p = 2401.0f * (0.01f * d) * (0.01f * d);
    const float C2p = 2401.0f * (0.03f * d) * (0.03f * d);
    const float cn  = 49.0f / 48.0f;

    float ring[6][5];   // horizontal sums of rows t..t+5 (compile-time indexed)
    float v[5];         // running vertical 7-row window sum
    #pragma unroll
    for (int q = 0; q < 5; ++q) v[q] = 0.0f;

    float ssum = 0.0f;

    #pragma unroll
    for (int r = 0; r < RPB + 6; ++r) {
        int rr = r0 + r;
        if (r >= RPB) rr = min(rr, WW - 1);       // only last band can overflow
        const int off = rr * WW + cl;

        // 4 coalesced scalar loads (one per plane)
        const float x0 = X0[off];
        const float x1 = X1[off];
        const float y0 = Y0[off];
        const float y1 = Y1[off];

        // channel-combined moments (per column)
        const float m0 = x0 + x1;
        const float m1 = y0 + y1;
        const float m2 = fmaf(x1, x1, x0 * x0);
        const float m3 = fmaf(y1, y1, y0 * y0);
        const float m4 = fmaf(x1, y1, x0 * y0);

        // horizontal 7-tap sums via cross-lane tree
        float h[5];
        h[0] = hsum7(m0, lane);
        h[1] = hsum7(m1, lane);
        h[2] = hsum7(m2, lane);
        h[3] = hsum7(m3, lane);
        h[4] = hsum7(m4, lane);

        if (r < 6) {
            #pragma unroll
            for (int q = 0; q < 5; ++q) { ring[r][q] = h[q]; v[q] += h[q]; }
        } else {
            #pragma unroll
            for (int q = 0; q < 5; ++q) v[q] += h[q];

            const int orow = r0 + r - 6;
            if (oval && orow < OHEI) {
                const float V0 = v[0], V1 = v[1], V2 = v[2], V3 = v[3], V4 = v[4];
                const float t01 = V0 * V1;
                const float t00 = V0 * V0;
                const float t11 = V1 * V1;
                const float A1  = 2.0f * t01 + C1p;
                const float A2  = fmaf(2.0f * cn, fmaf(49.0f, V4, -t01), C2p);
                const float B1  = t00 + t11 + C1p;
                const float p0  = fmaf(49.0f, V2, -t00);
                const float p1  = fmaf(49.0f, V3, -t11);
                const float B2  = fmaf(cn, p0 + p1, C2p);
                ssum += (A1 * A2) * __builtin_amdgcn_rcpf(B1 * B2);
            }

            #pragma unroll
            for (int q = 0; q < 5; ++q) {
                v[q] -= ring[(r - 6) % 6][q];
                ring[(r - 6) % 6][q] = h[q];
            }
        }
    }

    // ---- reduction: wave shuffle (double) -> LDS -> one atomic per block ----
    double local = (double)ssum;
    #pragma unroll
    for (int off = 32; off > 0; off >>= 1)
        local += __shfl_down(local, off, 64);
    __shared__ double wsum[NTH / 64];
    const int wid = threadIdx.x >> 6;
    if (lane == 0) wsum[wid] = local;
    __syncthreads();
    if (threadIdx.x == 0) {
        double tot = (wsum[0] + wsum[1]) + (wsum[2] + wsum[3]);
        atomicAdd(acc, tot);
        __threadfence();
        unsigned ticket = atomicAdd(counter, 1u);
        if (ticket == NBLK - 1) {
            double stot = atomicAdd(acc, 0.0);   // device-scope coherent read
            const double N = (double)BB * (double)OHEI * (double)OWID;
            out[0] = (float)(1.0 - stot / N);
        }
    }
}

extern "C" void kernel_launch(void* const* d_in, const int* in_sizes, int n_in,
                              void* d_out, int out_size, void* d_ws, size_t ws_size,
                              hipStream_t stream)
{
    const float* X  = (const float*)d_in[0];
    const float* Y  = (const float*)d_in[1];
    const float* dr = (const float*)d_in[2];
    // d_in[3] is the box kernel w (all 1/49) — folded into constants.
    double*   acc     = (double*)d_ws;
    unsigned* counter = (unsigned*)((char*)d_ws + 8);
    float*    out     = (float*)d_out;

    hipMemsetAsync(d_ws, 0, 16, stream);
    ssim_main<<<dim3(NBLK), dim3(NTH), 0, stream>>>(X, Y, dr, acc, counter, out);
}

// Round 7
// 213.468 us; speedup vs baseline: 1.5080x; 1.0311x over previous
//
#include <hip/hip_runtime.h>

#define WW 320          // input width/height
#define OWID 314        // output cols
#define OHEI 314        // output rows
#define BB 64           // batch
#define RPB 16          // output rows per wave-unit
#define NBAND 20        // ceil(314/16)
#define CGW 58          // output cols per wave (64 lanes, 58 valid windows)
#define NCG 6           // ceil(314/58)
#define NTH 256
#define WPB 4           // waves per block
#define NWU (BB * NCG * NBAND)   // 7680 wave-units
#define NBLK (NWU / WPB)         // 1920 exactly

__global__ __launch_bounds__(NTH, 6) void ssim_main(
    const float* __restrict__ X, const float* __restrict__ Y,
    const float* __restrict__ dr, double* __restrict__ acc,
    unsigned* __restrict__ counter, float* __restrict__ out)
{
    // wave-private, double-buffered horizontal-stage strips: [wave][buf][moment][col]
    __shared__ float hsb[WPB][2][5][64];     // 10240 B
    __shared__ double wsum[NTH / 64];

    const int lane = threadIdx.x & 63;
    const int wid  = threadIdx.x >> 6;
    const int wu   = blockIdx.x * WPB + wid;
    const int band = wu % NBAND;
    const int g    = (wu / NBAND) % NCG;
    const int b    = wu / (NBAND * NCG);
    const int r0   = band * RPB;
    const int c    = g * CGW + lane;
    const int cl   = min(c, WW - 1);              // clamped load col
    const int cc   = min(lane, 57);               // clamped read base (in-strip)
    const bool oval = (lane < 58) && (c < OWID);  // this lane emits outputs

    const size_t plane = (size_t)WW * WW;
    const float* X0 = X + (size_t)b * 2 * plane;
    const float* X1 = X0 + plane;
    const float* Y0 = Y + (size_t)b * 2 * plane;
    const float* Y1 = Y0 + plane;

    // SSIM constants folded to raw-window-sum form (x49^2)
    const float d   = dr[b];
    const float C1p = 2401.0f * (0.01f * d) * (0.01f * d);
    const float C2p = 2401.0f * (0.03f * d) * (0.03f * d);
    const float cn  = 49.0f / 48.0f;

    float ring[6][5];   // per-column moments of rows t..t+5 (compile-time indexed)
    float v[5];         // running vertical 7-row sums for this lane's column
    #pragma unroll
    for (int q = 0; q < 5; ++q) v[q] = 0.0f;

    float ssum = 0.0f;

    #pragma unroll
    for (int r = 0; r < RPB + 6; ++r) {
        int rr = r0 + r;
        if (r >= RPB) rr = min(rr, WW - 1);       // only last band can overflow
        const int off = rr * WW + cl;

        // 4 coalesced scalar loads (one per plane)
        const float x0 = X0[off];
        const float x1 = X1[off];
        const float y0 = Y0[off];
        const float y1 = Y1[off];

        // channel-combined moments (per column)
        float mm[5];
        mm[0] = x0 + x1;
        mm[1] = y0 + y1;
        mm[2] = fmaf(x1, x1, x0 * x0);
        mm[3] = fmaf(y1, y1, y0 * y0);
        mm[4] = fmaf(x1, y1, x0 * y0);

        if (r < 6) {
            #pragma unroll
            for (int q = 0; q < 5; ++q) { ring[r][q] = mm[q]; v[q] += mm[q]; }
        } else {
            #pragma unroll
            for (int q = 0; q < 5; ++q) v[q] += mm[q];
            // v[q] now holds the vertical 7-row sum for rows orow..orow+6

            // ---- horizontal pass through wave-private LDS (no barrier) ----
            float* buf = &hsb[wid][r & 1][0][0];
            #pragma unroll
            for (int q = 0; q < 5; ++q) buf[q * 64 + lane] = v[q];

            float H[5];
            #pragma unroll
            for (int q = 0; q < 5; ++q) {
                const float* bq = &buf[q * 64 + cc];
                H[q] = ((bq[0] + bq[1]) + (bq[2] + bq[3])) + ((bq[4] + bq[5]) + bq[6]);
            }

            const int orow = r0 + r - 6;
            if (oval && orow < OHEI) {
                const float V0 = H[0], V1 = H[1], V2 = H[2], V3 = H[3], V4 = H[4];
                const float t01 = V0 * V1;
                const float t00 = V0 * V0;
                const float t11 = V1 * V1;
                const float A1  = 2.0f * t01 + C1p;
                const float A2  = fmaf(2.0f * cn, fmaf(49.0f, V4, -t01), C2p);
                const float B1  = t00 + t11 + C1p;
                const float p0  = fmaf(49.0f, V2, -t00);
                const float p1  = fmaf(49.0f, V3, -t11);
                const float B2  = fmaf(cn, p0 + p1, C2p);
                ssum += (A1 * A2) * __builtin_amdgcn_rcpf(B1 * B2);
            }

            #pragma unroll
            for (int q = 0; q < 5; ++q) {
                v[q] -= ring[(r - 6) % 6][q];
                ring[(r - 6) % 6][q] = mm[q];
            }
        }
    }

    // ---- reduction: wave shuffle (double) -> LDS -> one atomic per block ----
    double local = (double)ssum;
    #pragma unroll
    for (int off = 32; off > 0; off >>= 1)
        local += __shfl_down(local, off, 64);
    if (lane == 0) wsum[wid] = local;
    __syncthreads();
    if (threadIdx.x == 0) {
        double tot = (wsum[0] + wsum[1]) + (wsum[2] + wsum[3]);
        atomicAdd(acc, tot);
        __threadfence();
        unsigned ticket = atomicAdd(counter, 1u);
        if (ticket == NBLK - 1) {
            double stot = atomicAdd(acc, 0.0);   // device-scope coherent read
            const double N = (double)BB * (double)OHEI * (double)OWID;
            out[0] = (float)(1.0 - stot / N);
        }
    }
}

extern "C" void kernel_launch(void* const* d_in, const int* in_sizes, int n_in,
                              void* d_out, int out_size, void* d_ws, size_t ws_size,
                              hipStream_t stream)
{
    const float* X  = (const float*)d_in[0];
    const float* Y  = (const float*)d_in[1];
    const float* dr = (const float*)d_in[2];
    // d_in[3] is the box kernel w (all 1/49) — folded into constants.
    double*   acc     = (double*)d_ws;
    unsigned* counter = (unsigned*)((char*)d_ws + 8);
    float*    out     = (float*)d_out;

    hipMemsetAsync(d_ws, 0, 16, stream);
    ssim_main<<<dim3(NBLK), dim3(NTH), 0, stream>>>(X, Y, dr, acc, counter, out);
}